// Round 1
// baseline (525.753 us; speedup 1.0000x reference)
//
#include <hip/hip_runtime.h>

typedef _Float16 half8 __attribute__((ext_vector_type(8)));
typedef _Float16 half4 __attribute__((ext_vector_type(4)));
typedef float f32x4 __attribute__((ext_vector_type(4)));
typedef int int4v __attribute__((ext_vector_type(4)));

#define ROWS 32                 // 32 rows/block -> 512 blocks -> 2 blocks/CU overlap
#define NC (ROWS / 16)          // batch chunks of 16 per wave
#define HP 136                  // h row pitch (halfs): 128 + 8 pad; 272 B
#define HBUFSZ (ROWS * HP)
#define LOG2E 1.442695041f
#define MFMA(a,b,c) __builtin_amdgcn_mfma_f32_16x16x32_f16((a),(b),(c),0,0,0)

__global__ __launch_bounds__(512, 4)
void traj_gru(const float* __restrict__ history,
              const float* __restrict__ w_ih, const float* __restrict__ w_hh,
              const float* __restrict__ b_ih, const float* __restrict__ b_hh,
              const float* __restrict__ w1, const float* __restrict__ b1,
              const float* __restrict__ w2, const float* __restrict__ b2,
              float* __restrict__ out)
{
    __shared__ __align__(16) _Float16 hbuf[2 * HBUFSZ];     // 17,408 B; a1 aliases dead half
    __shared__ __align__(16) _Float16 xhist[50 * ROWS * 6]; // 19,200 B compact [t][row][6]
    __shared__ __align__(16) _Float16 xdec[ROWS * 8];       //    512 B
    __shared__ __align__(16) _Float16 w2f[4 * 4 * 16 * 8];  //  4,096 B => 41,216 total

    const int tid  = threadIdx.x;
    const int wave = tid >> 6;
    const int lane = tid & 63;
    const int ln16 = lane & 15;
    const int q    = lane >> 4;
    const int sw   = ln16 & 3;               // head-phase2 a1s read swizzle (round-7 pair)
    const int rowbase = blockIdx.x * ROWS;
    const int dbase = wave * 16;             // gru: wave's h-dims; head: wave's a1-dims
    const int bblk  = wave >> 1;             // head a1s write swizzle (round-7 pair)
    const int colin = ((wave & 1) << 4) | ln16;

    // ---- init LDS: zeros first, barrier, then fills ----
    for (int i = tid; i < 2 * HBUFSZ; i += 512) hbuf[i] = (_Float16)0;
    for (int i = tid; i < ROWS * 8; i += 512) xdec[i] = (_Float16)0;
    for (int i = tid; i < 4 * 4 * 16 * 8; i += 512) w2f[i] = (_Float16)0;
    __syncthreads();
    for (int idx = tid; idx < ROWS * 300; idx += 512) {
        int r = idx / 300, rem = idx - r * 300;
        int t = rem / 6, c = rem - t * 6;
        xhist[(t * ROWS + r) * 6 + c] = (_Float16)history[(rowbase + r) * 300 + rem];
    }
    if (tid < ROWS) xdec[tid * 8 + 6] = (_Float16)1.0f;   // decoder bias slot
    for (int idx = tid; idx < 6 * 128; idx += 512) {      // w2 -> B-frag layout (round-7)
        int n = idx >> 7, k = idx & 127;
        int kt = k >> 5, qq = (k >> 3) & 3, j = k & 7;
        w2f[((kt * 4 + qq) * 16 + n) * 8 + j] = (_Float16)w2[n * 128 + k];
    }

    // ---- persistent register fragments ----
    // GRU (transposed): A-side = weights, m=ln16 -> dim dbase+ln16, k=kt*32+q*8+j
    // r,z pre-scaled by -log2e (sigmoid = rcp(1+exp2)); n by -2log2e (tanh = 2rcp-1)
    half8 Wg[3][4];
    #pragma unroll
    for (int g = 0; g < 3; ++g) {
        float sc = (g < 2) ? -LOG2E : -2.0f * LOG2E;
        #pragma unroll
        for (int kt = 0; kt < 4; ++kt) {
            const float* p = w_hh + (g * 128 + dbase + ln16) * 128 + kt * 32 + q * 8;
            half8 v;
            #pragma unroll
            for (int j = 0; j < 8; ++j) v[j] = (_Float16)(p[j] * sc);
            Wg[g][kt] = v;
        }
    }
    half8 Wx[3];     // A-side x-weights: q==0 rows k<6; bias via acc init
    #pragma unroll
    for (int g = 0; g < 3; ++g) {
        float sc = (g < 2) ? -LOG2E : -2.0f * LOG2E;
        half8 v;
        #pragma unroll
        for (int j = 0; j < 8; ++j) v[j] = (_Float16)0.0f;
        if (q == 0) {
            #pragma unroll
            for (int j = 0; j < 6; ++j) v[j] = (_Float16)(w_ih[(g * 128 + dbase + ln16) * 6 + j] * sc);
        }
        Wx[g] = v;
    }
    // gru biases -> acc init, element i -> C row = dim dbase+q*4+i
    f32x4 brr, brz, bin, bhn;
    #pragma unroll
    for (int i = 0; i < 4; ++i) {
        int d = dbase + q * 4 + i;
        brr[i] = (b_ih[d]       + b_hh[d]      ) * (-LOG2E);
        brz[i] = (b_ih[128 + d] + b_hh[128 + d]) * (-LOG2E);
        bin[i] = b_ih[256 + d] * (-2.0f * LOG2E);
        bhn[i] = b_hh[256 + d] * (-2.0f * LOG2E);
    }
    // HEAD (round-7 orientation): B-side w1, n=ln16 -> a1-dim dbase+ln16
    half8 Bw1[4];
    #pragma unroll
    for (int kt = 0; kt < 4; ++kt) {
        const float* p = w1 + (dbase + ln16) * 128 + kt * 32 + q * 8;
        half8 v;
        #pragma unroll
        for (int j = 0; j < 8; ++j) v[j] = (_Float16)p[j];
        Bw1[kt] = v;
    }
    const float b1r = b1[dbase + ln16];
    const float b2r = (ln16 < 6) ? b2[ln16] : 0.0f;

    float hp[NC][4] = {};  // h_prev: lane holds (batch=c*16+ln16, dim=dbase+q*4+i)

    __syncthreads();

    // ---- transposed GRU step: C[dim][batch], contiguous half4 h-writes ----
    auto gru_step = [&](int p, int t, bool enc) {
        const _Float16* hb = hbuf + p * HBUFSZ;
        _Float16*       hn = hbuf + (p ^ 1) * HBUFSZ;
        half8 Bf[2][4], Bx[2];
        f32x4 ar[2], az[2], ahh[2], an[2];

        auto loadB = [&](int c, int buf) {
            const _Float16* rp = hb + (c * 16 + ln16) * HP;
            #pragma unroll
            for (int kt = 0; kt < 4; ++kt)
                Bf[buf][kt] = *(const half8*)(rp + kt * 32 + q * 8);
            if (enc) {   // clean broadcast: registers only, no junk, no overread
                const int* xi = (const int*)xhist;
                int base = (t * ROWS + c * 16 + ln16) * 3;
                int4v d = { xi[base], xi[base + 1], xi[base + 2], 0x3C00 }; // [x0..x5,1,0]
                Bx[buf] = __builtin_bit_cast(half8, d);
            } else {
                Bx[buf] = *(const half8*)(xdec + (c * 16 + ln16) * 8);      // broadcast
            }
        };
        auto mfmas = [&](int buf) {
            f32x4 r = brr, z = brz, hh = bhn, n = bin;
            #pragma unroll
            for (int kt = 0; kt < 4; ++kt) {
                r  = MFMA(Wg[0][kt], Bf[buf][kt], r);
                z  = MFMA(Wg[1][kt], Bf[buf][kt], z);
                hh = MFMA(Wg[2][kt], Bf[buf][kt], hh);
            }
            r = MFMA(Wx[0], Bx[buf], r);
            z = MFMA(Wx[1], Bx[buf], z);
            n = MFMA(Wx[2], Bx[buf], n);
            ar[buf] = r; az[buf] = z; ahh[buf] = hh; an[buf] = n;
        };
        auto gates = [&](int c, int cb) {
            half4 hv;
            #pragma unroll
            for (int i = 0; i < 4; ++i) {
                float r = __builtin_amdgcn_rcpf(1.0f + __builtin_amdgcn_exp2f(ar[cb][i]));
                float z = __builtin_amdgcn_rcpf(1.0f + __builtin_amdgcn_exp2f(az[cb][i]));
                float tt = an[cb][i] + r * ahh[cb][i];
                float n = 2.0f * __builtin_amdgcn_rcpf(1.0f + __builtin_amdgcn_exp2f(tt)) - 1.0f;
                float h = n + z * (hp[c][i] - n);
                hp[c][i] = h;
                hv[i] = (_Float16)h;
            }
            *(half4*)(hn + (c * 16 + ln16) * HP + dbase + q * 4) = hv;
        };

        loadB(0, 0); mfmas(0);
        #pragma unroll
        for (int c = 0; c < NC; ++c) {
            const int cb = c & 1;
            if (c < NC - 1) { loadB(c + 1, cb ^ 1); mfmas(cb ^ 1); }
            gates(c, cb);
        }
        __syncthreads();
    };

    // ---- head step: byte-for-byte round-7 (verified), h read is plain layout ----
    auto head_step = [&](int f, int p) {
        const _Float16* hb = hbuf + p * HBUFSZ;
        _Float16*       a1 = hbuf + (p ^ 1) * HBUFSZ;   // dead ping-pong half
        half8 Ah[2][4];
        f32x4 aa[2];
        auto loadA = [&](int c, int buf) {
            const _Float16* rp = hb + (c * 16 + ln16) * HP;
            #pragma unroll
            for (int kt = 0; kt < 4; ++kt)
                Ah[buf][kt] = *(const half8*)(rp + kt * 32 + q * 8);   // plain [batch][dim]
        };
        auto mfh = [&](int buf) {
            f32x4 a = {0,0,0,0};
            #pragma unroll
            for (int kt = 0; kt < 4; ++kt) a = MFMA(Ah[buf][kt], Bw1[kt], a);
            aa[buf] = a;
        };
        auto relu4 = [&](int c, int cb) {
            #pragma unroll
            for (int i = 0; i < 4; ++i) {
                float v = aa[cb][i] + b1r;
                v = v > 0.0f ? v : 0.0f;
                a1[(c * 16 + q * 4 + i) * HP + ((bblk ^ i) << 5) + colin] = (_Float16)v;
            }
        };
        loadA(0, 0); mfh(0);
        #pragma unroll
        for (int c = 0; c < NC; ++c) {
            const int cb = c & 1;
            if (c < NC - 1) { loadA(c + 1, cb ^ 1); mfh(cb ^ 1); }
            relu4(c, cb);
        }
        __syncthreads();
        if (wave < NC) {   // round-7 phase 2: A=a1 (m=batch), B=w2f (n=out-dim)
            const _Float16* rp = a1 + (wave * 16 + ln16) * HP;
            f32x4 o = {0,0,0,0};
            #pragma unroll
            for (int kt = 0; kt < 4; ++kt) {
                half8 Aa = *(const half8*)(rp + ((kt ^ sw) << 5) + q * 8);
                half8 Bw = *(const half8*)&w2f[((kt * 4 + q) * 16 + ln16) * 8];
                o = MFMA(Aa, Bw, o);
            }
            if (ln16 < 6) {
                #pragma unroll
                for (int i = 0; i < 4; ++i) {
                    int row = wave * 16 + q * 4 + i;
                    float v = o[i] + b2r;
                    out[(rowbase + row) * 180 + f * 6 + ln16] = v;
                    xdec[row * 8 + ln16] = (_Float16)v;   // next decoder x (slots 0..5)
                }
            }
        }
        __syncthreads();
    };

    int p = 0;
    #pragma unroll 1
    for (int t = 0; t < 50; ++t) { gru_step(p, t, true); p ^= 1; }
    #pragma unroll 1
    for (int f = 0; f < 30; ++f) {
        gru_step(p, f == 0 ? 49 : 0, f == 0);   // f=0: x = history[:,49]
        p ^= 1;
        head_step(f, p);
    }
}

extern "C" void kernel_launch(void* const* d_in, const int* in_sizes, int n_in,
                              void* d_out, int out_size, void* d_ws, size_t ws_size,
                              hipStream_t stream) {
    (void)in_sizes; (void)n_in; (void)d_ws; (void)ws_size; (void)out_size;
    traj_gru<<<dim3(16384 / ROWS), dim3(512), 0, stream>>>(
        (const float*)d_in[0], (const float*)d_in[1], (const float*)d_in[2],
        (const float*)d_in[3], (const float*)d_in[4], (const float*)d_in[5],
        (const float*)d_in[6], (const float*)d_in[7], (const float*)d_in[8],
        (float*)d_out);
}

// Round 2
// 294.702 us; speedup vs baseline: 1.7840x; 1.7840x over previous
//
#include <hip/hip_runtime.h>

typedef _Float16 half8 __attribute__((ext_vector_type(8)));
typedef _Float16 half4 __attribute__((ext_vector_type(4)));
typedef float f32x4 __attribute__((ext_vector_type(4)));
typedef int int4v __attribute__((ext_vector_type(4)));

#define ROWS 32                 // 32 rows/block -> 512 blocks -> 2 blocks/CU overlap
#define NC (ROWS / 16)          // batch chunks of 16 per wave
#define HP 136                  // h row pitch (halfs): 128 + 8 pad; 272 B
#define HBUFSZ (ROWS * HP)
#define LOG2E 1.442695041f
#define MFMA(a,b,c) __builtin_amdgcn_mfma_f32_16x16x32_f16((a),(b),(c),0,0,0)

// NOTE: arg2 is interpreted as min BLOCKS/CU by hipcc (round-1 evidence:
// (512,4) -> VGPR capped at 64 -> spill catastrophe). (512,2) -> cap 128.
__global__ __launch_bounds__(512, 2)
void traj_gru(const float* __restrict__ history,
              const float* __restrict__ w_ih, const float* __restrict__ w_hh,
              const float* __restrict__ b_ih, const float* __restrict__ b_hh,
              const float* __restrict__ w1, const float* __restrict__ b1,
              const float* __restrict__ w2, const float* __restrict__ b2,
              float* __restrict__ out)
{
    __shared__ __align__(16) _Float16 hbuf[2 * HBUFSZ];     // 17,408 B; a1 aliases dead half
    __shared__ __align__(16) _Float16 xhist[50 * ROWS * 6]; // 19,200 B compact [t][row][6]
    __shared__ __align__(16) _Float16 xdec[ROWS * 8];       //    512 B
    __shared__ __align__(16) _Float16 w2f[4 * 4 * 16 * 8];  //  4,096 B => 41,216 total

    const int tid  = threadIdx.x;
    const int wave = tid >> 6;
    const int lane = tid & 63;
    const int ln16 = lane & 15;
    const int q    = lane >> 4;
    const int sw   = ln16 & 3;               // head-phase2 a1s read swizzle (round-7 pair)
    const int rowbase = blockIdx.x * ROWS;
    const int dbase = wave * 16;             // gru: wave's h-dims; head: wave's a1-dims
    const int bblk  = wave >> 1;             // head a1s write swizzle (round-7 pair)
    const int colin = ((wave & 1) << 4) | ln16;

    // ---- init LDS: zeros first, barrier, then fills ----
    for (int i = tid; i < 2 * HBUFSZ; i += 512) hbuf[i] = (_Float16)0;
    for (int i = tid; i < ROWS * 8; i += 512) xdec[i] = (_Float16)0;
    for (int i = tid; i < 4 * 4 * 16 * 8; i += 512) w2f[i] = (_Float16)0;
    __syncthreads();
    for (int idx = tid; idx < ROWS * 300; idx += 512) {
        int r = idx / 300, rem = idx - r * 300;
        int t = rem / 6, c = rem - t * 6;
        xhist[(t * ROWS + r) * 6 + c] = (_Float16)history[(rowbase + r) * 300 + rem];
    }
    if (tid < ROWS) xdec[tid * 8 + 6] = (_Float16)1.0f;   // decoder bias slot
    for (int idx = tid; idx < 6 * 128; idx += 512) {      // w2 -> B-frag layout (round-7)
        int n = idx >> 7, k = idx & 127;
        int kt = k >> 5, qq = (k >> 3) & 3, j = k & 7;
        w2f[((kt * 4 + qq) * 16 + n) * 8 + j] = (_Float16)w2[n * 128 + k];
    }

    // ---- persistent register fragments ----
    // GRU (transposed): A-side = weights, m=ln16 -> dim dbase+ln16, k=kt*32+q*8+j
    // r,z pre-scaled by -log2e (sigmoid = rcp(1+exp2)); n by -2log2e (tanh = 2rcp-1)
    half8 Wg[3][4];
    #pragma unroll
    for (int g = 0; g < 3; ++g) {
        float sc = (g < 2) ? -LOG2E : -2.0f * LOG2E;
        #pragma unroll
        for (int kt = 0; kt < 4; ++kt) {
            const float* p = w_hh + (g * 128 + dbase + ln16) * 128 + kt * 32 + q * 8;
            half8 v;
            #pragma unroll
            for (int j = 0; j < 8; ++j) v[j] = (_Float16)(p[j] * sc);
            Wg[g][kt] = v;
        }
    }
    half8 Wx[3];     // A-side x-weights: q==0 rows k<6; bias via acc init
    #pragma unroll
    for (int g = 0; g < 3; ++g) {
        float sc = (g < 2) ? -LOG2E : -2.0f * LOG2E;
        half8 v;
        #pragma unroll
        for (int j = 0; j < 8; ++j) v[j] = (_Float16)0.0f;
        if (q == 0) {
            #pragma unroll
            for (int j = 0; j < 6; ++j) v[j] = (_Float16)(w_ih[(g * 128 + dbase + ln16) * 6 + j] * sc);
        }
        Wx[g] = v;
    }
    // gru biases -> acc init, element i -> C row = dim dbase+q*4+i
    f32x4 brr, brz, bin, bhn;
    #pragma unroll
    for (int i = 0; i < 4; ++i) {
        int d = dbase + q * 4 + i;
        brr[i] = (b_ih[d]       + b_hh[d]      ) * (-LOG2E);
        brz[i] = (b_ih[128 + d] + b_hh[128 + d]) * (-LOG2E);
        bin[i] = b_ih[256 + d] * (-2.0f * LOG2E);
        bhn[i] = b_hh[256 + d] * (-2.0f * LOG2E);
    }
    // HEAD (round-7 orientation): B-side w1, n=ln16 -> a1-dim dbase+ln16
    half8 Bw1[4];
    #pragma unroll
    for (int kt = 0; kt < 4; ++kt) {
        const float* p = w1 + (dbase + ln16) * 128 + kt * 32 + q * 8;
        half8 v;
        #pragma unroll
        for (int j = 0; j < 8; ++j) v[j] = (_Float16)p[j];
        Bw1[kt] = v;
    }
    const float b1r = b1[dbase + ln16];
    const float b2r = (ln16 < 6) ? b2[ln16] : 0.0f;

    float hp[NC][4] = {};  // h_prev: lane holds (batch=c*16+ln16, dim=dbase+q*4+i)

    __syncthreads();

    // ---- transposed GRU step: C[dim][batch], contiguous half4 h-writes ----
    auto gru_step = [&](int p, int t, bool enc) {
        const _Float16* hb = hbuf + p * HBUFSZ;
        _Float16*       hn = hbuf + (p ^ 1) * HBUFSZ;
        half8 Bf[2][4], Bx[2];
        f32x4 ar[2], az[2], ahh[2], an[2];

        auto loadB = [&](int c, int buf) {
            const _Float16* rp = hb + (c * 16 + ln16) * HP;
            #pragma unroll
            for (int kt = 0; kt < 4; ++kt)
                Bf[buf][kt] = *(const half8*)(rp + kt * 32 + q * 8);
            if (enc) {   // clean broadcast: registers only, no junk, no overread
                const int* xi = (const int*)xhist;
                int base = (t * ROWS + c * 16 + ln16) * 3;
                int4v d = { xi[base], xi[base + 1], xi[base + 2], 0x3C00 }; // [x0..x5,1,0]
                Bx[buf] = __builtin_bit_cast(half8, d);
            } else {
                Bx[buf] = *(const half8*)(xdec + (c * 16 + ln16) * 8);      // broadcast
            }
        };
        auto mfmas = [&](int buf) {
            f32x4 r = brr, z = brz, hh = bhn, n = bin;
            #pragma unroll
            for (int kt = 0; kt < 4; ++kt) {
                r  = MFMA(Wg[0][kt], Bf[buf][kt], r);
                z  = MFMA(Wg[1][kt], Bf[buf][kt], z);
                hh = MFMA(Wg[2][kt], Bf[buf][kt], hh);
            }
            r = MFMA(Wx[0], Bx[buf], r);
            z = MFMA(Wx[1], Bx[buf], z);
            n = MFMA(Wx[2], Bx[buf], n);
            ar[buf] = r; az[buf] = z; ahh[buf] = hh; an[buf] = n;
        };
        auto gates = [&](int c, int cb) {
            half4 hv;
            #pragma unroll
            for (int i = 0; i < 4; ++i) {
                float r = __builtin_amdgcn_rcpf(1.0f + __builtin_amdgcn_exp2f(ar[cb][i]));
                float z = __builtin_amdgcn_rcpf(1.0f + __builtin_amdgcn_exp2f(az[cb][i]));
                float tt = an[cb][i] + r * ahh[cb][i];
                float n = 2.0f * __builtin_amdgcn_rcpf(1.0f + __builtin_amdgcn_exp2f(tt)) - 1.0f;
                float h = n + z * (hp[c][i] - n);
                hp[c][i] = h;
                hv[i] = (_Float16)h;
            }
            *(half4*)(hn + (c * 16 + ln16) * HP + dbase + q * 4) = hv;
        };

        loadB(0, 0); mfmas(0);
        #pragma unroll
        for (int c = 0; c < NC; ++c) {
            const int cb = c & 1;
            if (c < NC - 1) { loadB(c + 1, cb ^ 1); mfmas(cb ^ 1); }
            gates(c, cb);
        }
        __syncthreads();
    };

    // ---- head step: byte-for-byte round-7 (verified), h read is plain layout ----
    auto head_step = [&](int f, int p) {
        const _Float16* hb = hbuf + p * HBUFSZ;
        _Float16*       a1 = hbuf + (p ^ 1) * HBUFSZ;   // dead ping-pong half
        half8 Ah[2][4];
        f32x4 aa[2];
        auto loadA = [&](int c, int buf) {
            const _Float16* rp = hb + (c * 16 + ln16) * HP;
            #pragma unroll
            for (int kt = 0; kt < 4; ++kt)
                Ah[buf][kt] = *(const half8*)(rp + kt * 32 + q * 8);   // plain [batch][dim]
        };
        auto mfh = [&](int buf) {
            f32x4 a = {0,0,0,0};
            #pragma unroll
            for (int kt = 0; kt < 4; ++kt) a = MFMA(Ah[buf][kt], Bw1[kt], a);
            aa[buf] = a;
        };
        auto relu4 = [&](int c, int cb) {
            #pragma unroll
            for (int i = 0; i < 4; ++i) {
                float v = aa[cb][i] + b1r;
                v = v > 0.0f ? v : 0.0f;
                a1[(c * 16 + q * 4 + i) * HP + ((bblk ^ i) << 5) + colin] = (_Float16)v;
            }
        };
        loadA(0, 0); mfh(0);
        #pragma unroll
        for (int c = 0; c < NC; ++c) {
            const int cb = c & 1;
            if (c < NC - 1) { loadA(c + 1, cb ^ 1); mfh(cb ^ 1); }
            relu4(c, cb);
        }
        __syncthreads();
        if (wave < NC) {   // round-7 phase 2: A=a1 (m=batch), B=w2f (n=out-dim)
            const _Float16* rp = a1 + (wave * 16 + ln16) * HP;
            f32x4 o = {0,0,0,0};
            #pragma unroll
            for (int kt = 0; kt < 4; ++kt) {
                half8 Aa = *(const half8*)(rp + ((kt ^ sw) << 5) + q * 8);
                half8 Bw = *(const half8*)&w2f[((kt * 4 + q) * 16 + ln16) * 8];
                o = MFMA(Aa, Bw, o);
            }
            if (ln16 < 6) {
                #pragma unroll
                for (int i = 0; i < 4; ++i) {
                    int row = wave * 16 + q * 4 + i;
                    float v = o[i] + b2r;
                    out[(rowbase + row) * 180 + f * 6 + ln16] = v;
                    xdec[row * 8 + ln16] = (_Float16)v;   // next decoder x (slots 0..5)
                }
            }
        }
        __syncthreads();
    };

    int p = 0;
    #pragma unroll 1
    for (int t = 0; t < 50; ++t) { gru_step(p, t, true); p ^= 1; }
    #pragma unroll 1
    for (int f = 0; f < 30; ++f) {
        gru_step(p, f == 0 ? 49 : 0, f == 0);   // f=0: x = history[:,49]
        p ^= 1;
        head_step(f, p);
    }
}

extern "C" void kernel_launch(void* const* d_in, const int* in_sizes, int n_in,
                              void* d_out, int out_size, void* d_ws, size_t ws_size,
                              hipStream_t stream) {
    (void)in_sizes; (void)n_in; (void)d_ws; (void)ws_size; (void)out_size;
    traj_gru<<<dim3(16384 / ROWS), dim3(512), 0, stream>>>(
        (const float*)d_in[0], (const float*)d_in[1], (const float*)d_in[2],
        (const float*)d_in[3], (const float*)d_in[4], (const float*)d_in[5],
        (const float*)d_in[6], (const float*)d_in[7], (const float*)d_in[8],
        (float*)d_out);
}